// Round 10
// baseline (478.495 us; speedup 1.0000x reference)
//
#include <hip/hip_runtime.h>

// Problem constants (match reference)
constexpr int   T_STEPS = 64;
constexpr int   NN      = 2048;
constexpr float DT_TAU  = 0.1f;    // DT * TAU_MEM_INV
constexpr float V_TH_C  = 1.0f;
constexpr float TRC     = 0.05f;   // DT * TAU_PRE_INV == DT * TAU_POST_INV
constexpr float ETA     = 1e-3f;   // ETA_PLUS == ETA_MINUS

// 256 blocks x 512 threads (cooperative, 1 block/CU). Block b owns neurons
// [8b, 8b+8); wave w owns neuron 8b+w (w-row in 32 VGPR/lane). z/tp
// replicated per block in LDS (split-slot layout, r6), rebuilt each step.
//
// HARD-WON EXCHANGE RULES (r1/r2/r4/r5/r8/r9):
//  1. Private 128B line per published word (r2: 244->203).
//  2. EXACTLY 256 pollers/block (r5: 512/line -> +36us; agent-scope atomic
//     loads issue per-lane, no same-address merge).
//  3. Publish by the 8th arriver via LDS RMW (r4: 203->181).
//  4. NO scattered fan-out stores: push-mailboxes wrote 129MB to HBM via
//     per-store dirty lines (r9: 232us). Fan-in polling is cheaper.
//  5. LDS bank conflicts of 2-8M are hidden under the exchange wait (r4==r6).
//
// ROUND 10: hide phase C under the exchange wait (straggler tail).
// Chunk c (slots/neurons of blocks [32c,32c+32)) is consumable as soon as its
// 32 words arrived — not when ALL 256 arrived. Pollers flag each chunk
// (packed byte per chunk in done4_s, +1 per step, release); every wave
// consumes chunks IN ARRIVAL ORDER via a 2-load flag scan + static-index
// switch. Bit-exactness: the STDP update is per-chunk independent (any
// order); the acc reduction is DEFERRED — zj stashed per chunk, then
// acc += wreg[c].{x,y,z,w}*zst[c] in the ORIGINAL fixed order c=0..7/xyzw.
// Waves 0-3 poll (one word per lane, private lines; lane tid==bid reads the
// block's own word from LDS instead of MALL) and interleave one chunk
// consumption under each in-flight poll load. Waves 4-7 consume as flags
// land. ONE barrier/step (post-C).
//
// Ordering (one barrier): RAW via flag release->acquire (flag add waits
// lgkmcnt -> all 32 lanes' prior ds_writes complete). WAR: b(k+1) writes
// happen after barrier(k), which is after all waves consumed all 8 chunks
// at step k. Gating chain for the '!=' spin (unchanged): P overwrites its
// slot (tag k+3) at a(k+2), after P's barrier(k+1), after P's merged
// loop(k+1) consumed tag k+2 from ALL blocks, each of which required that
// block's merged loop(k) to have consumed tag k+1 -> never missed. word_s
// reset at a(k) reused at a(k+2): ordered by barriers k,k+1. Stale tags
// (0x00/0xAA poison, prior-run <=64) are overwritten before any aliasing
// expectation, as in r2-r6. No ws initialization needed.
constexpr int BLOCKS  = 256;
constexpr int THREADS = 512;
constexpr int ROWS_PER_BLOCK = NN / BLOCKS;   // 8 == waves per block
constexpr int CHUNKS = NN / 256;              // 8 float4 chunks per lane

__global__ __launch_bounds__(THREADS)
void snn_msg_kernel(const float* __restrict__ x,       // [T, N]
                    const float* __restrict__ w_in,    // [N, N] pristine (never written)
                    const float* __restrict__ tpre0,   // [N]
                    const float* __restrict__ tpost0,  // [N]
                    unsigned long long* __restrict__ zpub, // [2][BLOCKS*stride]
                    int stride,                        // u64 units between words
                    float*       __restrict__ out)     // [T, N] spikes
{
    const int bid  = blockIdx.x;
    const int tid  = threadIdx.x;
    const int wv   = tid >> 6;
    const int lane = tid & 63;
    const int row  = bid * ROWS_PER_BLOCK + wv;   // this wave's neuron / w row

    __shared__ __align__(16) float z_s[NN];       // spike vector (split-slot layout)
    __shared__ __align__(16) float tp_s[NN];      // pre-trace mirror (split-slot)
    __shared__ __align__(16) float x_s[T_STEPS * ROWS_PER_BLOCK]; // owned inputs
    __shared__ unsigned word_s[2];                // [parity] count<<24 | bits
    __shared__ unsigned long long ownword_s[2];   // [parity] own block's word
    __shared__ unsigned done4_s[2];               // 8 chunk flag BYTES (+1/step)

    // Poller tid (<256) owns neurons [8tid, 8tid+8): tp persistent in regs.
    float4 tpA = make_float4(0.f, 0.f, 0.f, 0.f);
    float4 tpB = tpA;
    if (tid < BLOCKS) {
        tpA = ((const float4*)tpre0)[2 * tid];
        tpB = ((const float4*)tpre0)[2 * tid + 1];
    }

    // Stage ALL owned inputs x[t][8b..8b+8) into LDS once.
    x_s[tid] = x[(size_t)(tid >> 3) * NN + bid * ROWS_PER_BLOCK + (tid & 7)];

    if (tid < 2) { word_s[tid] = 0u; done4_s[tid] = 0u; }

    // Own-neuron state, replicated across all 64 lanes.
    float v_own   = 0.0f;
    float tpo_own = tpost0[row];          // broadcast load

    // This wave's w row: chunk c holds w[row][(c*64+lane)*4 ..+3].
    const float4* wrow4 = (const float4*)(w_in + (size_t)row * NN);
    float4 wreg[CHUNKS];
    #pragma unroll
    for (int c = 0; c < CHUNKS; ++c) wreg[c] = wrow4[c * 64 + lane];

    // Per-lane constant base for the split-slot permutation (phase C reads).
    const int perm_base = (lane >> 1) + 256 * (lane & 1);
    const bool ownlocal = (tid == bid);   // poller of our own block's word

    float isyn = 0.0f;                    // w @ z carry, lives in registers
    float xk   = 0.0f;                    // prefetched input current
    __syncthreads();
    xk = x_s[wv];                         // x[0][row] (post-barrier: x_s ready)

    const float4* z4s  = (const float4*)z_s;
    const float4* tp4s = (const float4*)tp_s;

// ---- statically-indexed chunk body (rule: no runtime-indexed reg arrays) ----
#define PROC_CHUNK(c_)                                                         \
    {                                                                          \
        const int slot = (c_) * 32 + perm_base;                                \
        float4 zj = z4s[slot];                                                 \
        float4 tj = tp4s[slot];                                                \
        float nw;                                                              \
        nw = wreg[c_].x + (ETA * (zi_own * tj.x) - ETA * (tpoi * zj.x));       \
        nw = fminf(fmaxf(nw, 0.0f), 1.0f); wreg[c_].x = nw;                    \
        nw = wreg[c_].y + (ETA * (zi_own * tj.y) - ETA * (tpoi * zj.y));       \
        nw = fminf(fmaxf(nw, 0.0f), 1.0f); wreg[c_].y = nw;                    \
        nw = wreg[c_].z + (ETA * (zi_own * tj.z) - ETA * (tpoi * zj.z));       \
        nw = fminf(fmaxf(nw, 0.0f), 1.0f); wreg[c_].z = nw;                    \
        nw = wreg[c_].w + (ETA * (zi_own * tj.w) - ETA * (tpoi * zj.w));       \
        nw = fminf(fmaxf(nw, 0.0f), 1.0f); wreg[c_].w = nw;                    \
        zst[c_] = zj;                                                          \
    }

#define TRY_CONSUME()                                                          \
    {                                                                          \
        unsigned d0 = __hip_atomic_load(&done4_s[0], __ATOMIC_ACQUIRE,         \
                                        __HIP_MEMORY_SCOPE_WORKGROUP);         \
        unsigned d1 = __hip_atomic_load(&done4_s[1], __ATOMIC_ACQUIRE,         \
                                        __HIP_MEMORY_SCOPE_WORKGROUP);         \
        unsigned rm = 0;                                                       \
        rm |= (((d0 >>  0) & 0xFFu) == tag8) ? 0x01u : 0u;                     \
        rm |= (((d0 >>  8) & 0xFFu) == tag8) ? 0x02u : 0u;                     \
        rm |= (((d0 >> 16) & 0xFFu) == tag8) ? 0x04u : 0u;                     \
        rm |= (((d0 >> 24) & 0xFFu) == tag8) ? 0x08u : 0u;                     \
        rm |= (((d1 >>  0) & 0xFFu) == tag8) ? 0x10u : 0u;                     \
        rm |= (((d1 >>  8) & 0xFFu) == tag8) ? 0x20u : 0u;                     \
        rm |= (((d1 >> 16) & 0xFFu) == tag8) ? 0x40u : 0u;                     \
        rm |= (((d1 >> 24) & 0xFFu) == tag8) ? 0x80u : 0u;                     \
        rm &= ~(unsigned)processed;                                            \
        if (rm) {                                                              \
            int c_ = (int)__builtin_ctz(rm);                                   \
            switch (c_) {                                                      \
            case 0: PROC_CHUNK(0); break;                                      \
            case 1: PROC_CHUNK(1); break;                                      \
            case 2: PROC_CHUNK(2); break;                                      \
            case 3: PROC_CHUNK(3); break;                                      \
            case 4: PROC_CHUNK(4); break;                                      \
            case 5: PROC_CHUNK(5); break;                                      \
            case 6: PROC_CHUNK(6); break;                                      \
            default: PROC_CHUNK(7); break;                                     \
            }                                                                  \
            processed |= 1 << c_;                                              \
            did = true;                                                        \
        }                                                                      \
    }

    for (int k = 0; k < T_STEPS; ++k) {
        const int par = k & 1;

        // ---- a: LIF (all lanes redundantly); lane0 raster + arrive/publish ----
        float v = v_own + DT_TAU * ((0.0f - v_own) + isyn + xk);
        float z = (v - V_TH_C > 0.0f) ? 1.0f : 0.0f;
        v_own   = v * (1.0f - z);
        tpo_own = tpo_own + TRC * (-tpo_own + z);   // post-trace (post-update
                                                    // value feeds C, as in ref)
        if (lane == 0) {
            out[(size_t)k * NN + row] = z;          // fire-and-forget raster
            if (k + 1 < T_STEPS) {
                unsigned add = 0x01000000u | (z > 0.0f ? (1u << wv) : 0u);
                unsigned old = __hip_atomic_fetch_add(&word_s[par], add,
                                   __ATOMIC_RELAXED, __HIP_MEMORY_SCOPE_WORKGROUP);
                if ((old >> 24) == 7u) {            // 8th arriver publishes
                    unsigned bits = (old + add) & 0xFFu;
                    __hip_atomic_store(&word_s[par], 0u,
                                       __ATOMIC_RELAXED, __HIP_MEMORY_SCOPE_WORKGROUP);
                    unsigned long long wrd =
                        ((unsigned long long)(unsigned)(k + 1) << 32) | bits;
                    __hip_atomic_store(&ownword_s[par], wrd,
                                       __ATOMIC_RELAXED, __HIP_MEMORY_SCOPE_WORKGROUP);
                    __hip_atomic_store(&zpub[(size_t)(par * BLOCKS + bid) * stride],
                                       wrd, __ATOMIC_RELAXED,
                                       __HIP_MEMORY_SCOPE_AGENT);
                }
            }
        }
        if (k == T_STEPS - 1) break;   // raster[63] written; no exchange needed

        // ---- b+c merged: poll / flag / consume-in-arrival-order ----
        const float    zi_own = z;
        const float    tpoi   = tpo_own;
        const unsigned tag    = (unsigned)(k + 1);
        const unsigned tag8   = (unsigned)(k + 1);   // flag bytes: +1 per step
        float4 zst[CHUNKS];                          // static-indexed stash
        int processed = 0;

        if (wv < 4) {
            // polling wave: lanes poll word tid; interleave chunk consumption
            const unsigned long long* pollp =
                &zpub[(size_t)(par * BLOCKS + tid) * stride];
            bool mypend = true;
            bool flagLo = false, flagHi = false;
            while (processed != 0xFF || __ballot(mypend)) {
                bool did = false;
                unsigned long long pmask = __ballot(mypend);
                unsigned long long pv = 0;
                if (pmask && mypend) {
                    pv = ownlocal
                       ? __hip_atomic_load(&ownword_s[par], __ATOMIC_RELAXED,
                                           __HIP_MEMORY_SCOPE_WORKGROUP)
                       : __hip_atomic_load(pollp, __ATOMIC_RELAXED,
                                           __HIP_MEMORY_SCOPE_AGENT);
                }
                // consume one ready chunk while the poll load is in flight
                TRY_CONSUME();
                if (pmask) {
                    bool newready = mypend && ((unsigned)(pv >> 32) == tag);
                    if (newready) {
                        const unsigned bits = (unsigned)pv;
                        float4 zA, zB;
                        zA.x = (bits & 0x01u) ? 1.0f : 0.0f;
                        zA.y = (bits & 0x02u) ? 1.0f : 0.0f;
                        zA.z = (bits & 0x04u) ? 1.0f : 0.0f;
                        zA.w = (bits & 0x08u) ? 1.0f : 0.0f;
                        zB.x = (bits & 0x10u) ? 1.0f : 0.0f;
                        zB.y = (bits & 0x20u) ? 1.0f : 0.0f;
                        zB.z = (bits & 0x40u) ? 1.0f : 0.0f;
                        zB.w = (bits & 0x80u) ? 1.0f : 0.0f;
                        // identical per-element expression -> bit-exact
                        tpA.x = tpA.x + TRC * (-tpA.x + zA.x);
                        tpA.y = tpA.y + TRC * (-tpA.y + zA.y);
                        tpA.z = tpA.z + TRC * (-tpA.z + zA.z);
                        tpA.w = tpA.w + TRC * (-tpA.w + zA.w);
                        tpB.x = tpB.x + TRC * (-tpB.x + zB.x);
                        tpB.y = tpB.y + TRC * (-tpB.y + zB.y);
                        tpB.z = tpB.z + TRC * (-tpB.z + zB.z);
                        tpB.w = tpB.w + TRC * (-tpB.w + zB.w);
                        ((float4*)z_s)[tid]           = zA;
                        ((float4*)z_s)[tid + BLOCKS]  = zB;
                        ((float4*)tp_s)[tid]          = tpA;
                        ((float4*)tp_s)[tid + BLOCKS] = tpB;
                        mypend = false;
                        did = true;
                    }
                    unsigned long long pm2 = __ballot(mypend);
                    // chunk 2wv = lanes 0-31 (tid>>5), chunk 2wv+1 = lanes 32-63.
                    // flag add (release) waits lgkmcnt -> all prior ds_writes
                    // of this wave (all lanes) are complete first.
                    if (!flagLo && (pm2 & 0xFFFFFFFFull) == 0ull) {
                        if (lane == 0) {
                            const int cc = 2 * wv;
                            __hip_atomic_fetch_add(&done4_s[cc >> 2],
                                1u << (8 * (cc & 3)),
                                __ATOMIC_RELEASE, __HIP_MEMORY_SCOPE_WORKGROUP);
                        }
                        flagLo = true;
                    }
                    if (!flagHi && (pm2 >> 32) == 0ull) {
                        if (lane == 0) {
                            const int cc = 2 * wv + 1;
                            __hip_atomic_fetch_add(&done4_s[cc >> 2],
                                1u << (8 * (cc & 3)),
                                __ATOMIC_RELEASE, __HIP_MEMORY_SCOPE_WORKGROUP);
                        }
                        flagHi = true;
                    }
                }
                if (!did) __builtin_amdgcn_s_sleep(1);
            }
        } else {
            // pure consumer wave: process chunks as their flags land
            while (processed != 0xFF) {
                bool did = false;
                TRY_CONSUME();
                if (!did) __builtin_amdgcn_s_sleep(1);
            }
        }

        // ---- part2: DEFERRED acc reduction in the ORIGINAL fixed order ----
        // (c = 0..7, components x,y,z,w) -> bit-identical summation chain.
        float acc = 0.0f;
        #pragma unroll
        for (int c = 0; c < CHUNKS; ++c) {
            acc += wreg[c].x * zst[c].x;
            acc += wreg[c].y * zst[c].y;
            acc += wreg[c].z * zst[c].z;
            acc += wreg[c].w * zst[c].w;
        }
        #pragma unroll
        for (int m = 32; m >= 1; m >>= 1) acc += __shfl_xor(acc, m, 64);
        isyn = acc;                    // i_syn for step k+1, in registers
        xk = x_s[(k + 1) * ROWS_PER_BLOCK + wv];   // prefetch next input

        __syncthreads();   // the ONLY per-step barrier: all C(k) reads done
                           // before any b(k+1) write / a(k+1) arrival
    }
#undef TRY_CONSUME
#undef PROC_CHUNK
}

extern "C" void kernel_launch(void* const* d_in, const int* in_sizes, int n_in,
                              void* d_out, int out_size, void* d_ws, size_t ws_size,
                              hipStream_t stream) {
    const float* x     = (const float*)d_in[0];   // [T,N]
    const float* w_in  = (const float*)d_in[1];   // [N,N]
    const float* tpre  = (const float*)d_in[2];   // [N]
    const float* tpost = (const float*)d_in[3];   // [N]
    float*       out   = (float*)d_out;           // [T,N]

    unsigned long long* zpub = (unsigned long long*)d_ws;

    // Pad each published word to its own line if the workspace allows:
    // 128B stride (TCC line) needs 64KB, 64B needs 32KB, else packed (4KB).
    int stride;
    if      (ws_size >= (size_t)2 * BLOCKS * 16 * sizeof(unsigned long long)) stride = 16;
    else if (ws_size >= (size_t)2 * BLOCKS *  8 * sizeof(unsigned long long)) stride = 8;
    else                                                                      stride = 1;

    void* args[] = {(void*)&x, (void*)&w_in, (void*)&tpre, (void*)&tpost,
                    (void*)&zpub, (void*)&stride, (void*)&out};
    hipLaunchCooperativeKernel((void*)snn_msg_kernel,
                               dim3(BLOCKS), dim3(THREADS),
                               args, 0, stream);
}

// Round 11
// 313.703 us; speedup vs baseline: 1.5253x; 1.5253x over previous
//
#include <hip/hip_runtime.h>

// Problem constants (match reference)
constexpr int   T_STEPS = 64;
constexpr int   NN      = 2048;
constexpr float DT_TAU  = 0.1f;    // DT * TAU_MEM_INV
constexpr float V_TH_C  = 1.0f;
constexpr float TRC     = 0.05f;   // DT * TAU_PRE_INV == DT * TAU_POST_INV
constexpr float ETA     = 1e-3f;   // ETA_PLUS == ETA_MINUS

// 256 blocks x 512 threads (cooperative, 1 block/CU). Block b owns neurons
// [8b, 8b+8); wave w owns neuron 8b+w (w-row in 32 VGPR/lane; v/tpo/isyn
// replicated across its 64 lanes). z/tp replicated per block in LDS (split-
// slot layout), rebuilt each step from the published spike words.
//
// HARD-WON EXCHANGE RULES (r1/r2/r4/r5/r8/r9/r10):
//  1. Private 128B line per published word (r2: 244->203).
//  2. EXACTLY 256 pollers/block, one word each (r5: 512/line -> +36us;
//     agent-scope atomic loads issue per-lane, no same-address merge).
//  3. Publish by the 8th arriver via LDS RMW (r4: 203->181).
//  4. NO scattered fan-out stores (r9 push-mailboxes: 129MB HBM writeback,
//     +51us). Fan-in polling is cheaper than fan-out storing.
//  5. LDS bank conflicts of 2-8M are hidden under the exchange wait
//     (r4 2.58M == r6 8.26M == ~181us).
//  6. NO extra machinery in the exchange: poll-prefetch/one-barrier (r8,
//     +51us) and arrival-ordered consumption (r10, +221us) both lost to
//     their own overhead. The two-barrier pull skeleton below is the
//     empirical optimum across 10 structural variants.
//
// ROUND 11 = round-6 kernel verbatim + the ONE isolated lever left from the
// r7 bundle: the zi=0 fast path in phase C (pure work-removal on the serial
// chain, wave-uniform branch, cannot touch exchange pressure).
//
// Step k:
//  a. LIF from register isyn -> z; v,tpo in regs; lane0: raster store +
//     ds-atomic arrive on word_s[par] (add (1<<24)|(z<<wv)); 8th arriver
//     publishes ONE tagged u64 ((k+1)<<32|bits) to this block's line.
//  b. pollers tid<256 spin on word tid (tag k+1), unpack 8 neurons into
//     z_s split-slots (slot tid = neurons [8tid,8tid+4), slot tid+256 =
//     [8tid+4,8tid+8): both stores stride-1); tp persistent in poller regs.
//     __syncthreads  (RAW: b-writes visible before C-reads)
//  c. fused STDP w-update + matvec, split-slot permuted reads
//     (slot = c*32 + (lane>>1) + 256*(lane&1)), bit-exact c=0..7/xyzw order.
//     zi FAST PATH (wave-uniform): if own neuron didn't spike,
//     nw = zj ? clip(w - etp) : w with etp = ETA*tpoi — bit-exact because
//     tj,tpoi,w >= 0 invariants give ETA*(0*tj) = +0, w + (+0 - q) == w - q,
//     q|zj=1 = ETA*(tpoi*1) == etp, and clip(w) == w for w in [0,1]
//     (invariant). The tj LDS read is SKIPPED on this path. zi=1 branch
//     keeps the original expression verbatim. (Field-verified absmax 0.0
//     in r8's bundle.)
//     Butterfly -> isyn in regs; prefetch next x.
//     __syncthreads  (WAR: C-reads done before next b-writes; also orders
//                     word_s reset (a) before k+2 arrivals on that parity)
//
// Cross-block safety (unchanged): message==data (bits ride in the tagged
// word, single 8B atomic); tags 1..64 never match 0x00/0xAA poison; parity
// double-buffer + publish gating chain (publish(k+2) transitively requires
// every block's pollers consumed tag k+1) -> '!=' spin never misses; no ws
// initialization needed.
constexpr int BLOCKS  = 256;
constexpr int THREADS = 512;
constexpr int ROWS_PER_BLOCK = NN / BLOCKS;   // 8 == waves per block
constexpr int CHUNKS = NN / 256;              // 8 float4 chunks per lane

__global__ __launch_bounds__(THREADS)
void snn_msg_kernel(const float* __restrict__ x,       // [T, N]
                    const float* __restrict__ w_in,    // [N, N] pristine (never written)
                    const float* __restrict__ tpre0,   // [N]
                    const float* __restrict__ tpost0,  // [N]
                    unsigned long long* __restrict__ zpub, // [2][BLOCKS*stride]
                    int stride,                        // u64 units between words
                    float*       __restrict__ out)     // [T, N] spikes
{
    const int bid  = blockIdx.x;
    const int tid  = threadIdx.x;
    const int wv   = tid >> 6;
    const int lane = tid & 63;
    const int row  = bid * ROWS_PER_BLOCK + wv;   // this wave's neuron / w row

    __shared__ __align__(16) float z_s[NN];       // spike vector (split-slot layout)
    __shared__ __align__(16) float tp_s[NN];      // pre-trace mirror (split-slot)
    __shared__ __align__(16) float x_s[T_STEPS * ROWS_PER_BLOCK]; // owned inputs
    __shared__ unsigned word_s[2];                // [parity] count<<24 | bits

    // Poller tid (<256) owns neurons [8tid, 8tid+8): tp persistent in regs.
    float4 tpA = make_float4(0.f, 0.f, 0.f, 0.f);
    float4 tpB = tpA;
    if (tid < BLOCKS) {
        tpA = ((const float4*)tpre0)[2 * tid];
        tpB = ((const float4*)tpre0)[2 * tid + 1];
    }

    // Stage ALL owned inputs x[t][8b..8b+8) into LDS once.
    x_s[tid] = x[(size_t)(tid >> 3) * NN + bid * ROWS_PER_BLOCK + (tid & 7)];

    if (tid < 2) word_s[tid] = 0u;

    // Own-neuron state, replicated across all 64 lanes.
    float v_own   = 0.0f;
    float tpo_own = tpost0[row];          // broadcast load

    // This wave's w row: chunk c holds w[row][(c*64+lane)*4 ..+3].
    const float4* wrow4 = (const float4*)(w_in + (size_t)row * NN);
    float4 wreg[CHUNKS];
    #pragma unroll
    for (int c = 0; c < CHUNKS; ++c) wreg[c] = wrow4[c * 64 + lane];

    // Per-lane constant base for the split-slot permutation (phase C reads).
    const int perm_base = (lane >> 1) + 256 * (lane & 1);

    float isyn = 0.0f;                    // w @ z carry, lives in registers
    float xk   = 0.0f;                    // prefetched input current
    __syncthreads();
    xk = x_s[wv];                         // x[0][row] (post-barrier: x_s ready)

    for (int k = 0; k < T_STEPS; ++k) {
        const int par = k & 1;

        // ---- a: LIF (all lanes redundantly); lane0 raster + arrive/publish ----
        float v = v_own + DT_TAU * ((0.0f - v_own) + isyn + xk);
        float z = (v - V_TH_C > 0.0f) ? 1.0f : 0.0f;
        v_own   = v * (1.0f - z);
        tpo_own = tpo_own + TRC * (-tpo_own + z);   // post-trace (post-update
                                                    // value feeds C, as in ref)
        if (lane == 0) {
            out[(size_t)k * NN + row] = z;          // fire-and-forget raster
            if (k + 1 < T_STEPS) {
                unsigned add = 0x01000000u | (z > 0.0f ? (1u << wv) : 0u);
                unsigned old = __hip_atomic_fetch_add(&word_s[par], add,
                                   __ATOMIC_RELAXED, __HIP_MEMORY_SCOPE_WORKGROUP);
                if ((old >> 24) == 7u) {            // 8th arriver publishes
                    unsigned bits = (old + add) & 0xFFu;
                    // reset for reuse at k+2; ordered before k+2 arrivals by
                    // the post-b and post-C barriers of iterations k and k+1.
                    __hip_atomic_store(&word_s[par], 0u,
                                       __ATOMIC_RELAXED, __HIP_MEMORY_SCOPE_WORKGROUP);
                    unsigned long long wrd =
                        ((unsigned long long)(unsigned)(k + 1) << 32) | bits;
                    __hip_atomic_store(&zpub[(size_t)(par * BLOCKS + bid) * stride],
                                       wrd, __ATOMIC_RELAXED,
                                       __HIP_MEMORY_SCOPE_AGENT);
                }
            }
        }
        if (k == T_STEPS - 1) break;   // raster[63] written; no exchange needed

        // ---- b: 256 pollers, one word each; in-place unpack to split slots ----
        if (tid < BLOCKS) {
            const unsigned long long* p =
                &zpub[(size_t)(par * BLOCKS + tid) * stride];
            unsigned long long pv = __hip_atomic_load(p, __ATOMIC_RELAXED,
                                        __HIP_MEMORY_SCOPE_AGENT);
            while ((unsigned)(pv >> 32) != (unsigned)(k + 1)) {
                __builtin_amdgcn_s_sleep(1);   // ~64cy backoff
                pv = __hip_atomic_load(p, __ATOMIC_RELAXED,
                                       __HIP_MEMORY_SCOPE_AGENT);
            }
            const unsigned bits = (unsigned)pv;   // z of neurons 8*tid..8*tid+7
            float4 zA, zB;
            zA.x = (bits & 0x01u) ? 1.0f : 0.0f;
            zA.y = (bits & 0x02u) ? 1.0f : 0.0f;
            zA.z = (bits & 0x04u) ? 1.0f : 0.0f;
            zA.w = (bits & 0x08u) ? 1.0f : 0.0f;
            zB.x = (bits & 0x10u) ? 1.0f : 0.0f;
            zB.y = (bits & 0x20u) ? 1.0f : 0.0f;
            zB.z = (bits & 0x40u) ? 1.0f : 0.0f;
            zB.w = (bits & 0x80u) ? 1.0f : 0.0f;
            // identical per-element expression as always -> bit-exact
            tpA.x = tpA.x + TRC * (-tpA.x + zA.x);
            tpA.y = tpA.y + TRC * (-tpA.y + zA.y);
            tpA.z = tpA.z + TRC * (-tpA.z + zA.z);
            tpA.w = tpA.w + TRC * (-tpA.w + zA.w);
            tpB.x = tpB.x + TRC * (-tpB.x + zB.x);
            tpB.y = tpB.y + TRC * (-tpB.y + zB.y);
            tpB.z = tpB.z + TRC * (-tpB.z + zB.z);
            tpB.w = tpB.w + TRC * (-tpB.w + zB.w);
            // split-slot stores: both instructions stride-1 across the wave
            ((float4*)z_s)[tid]          = zA;
            ((float4*)z_s)[tid + BLOCKS] = zB;
            ((float4*)tp_s)[tid]          = tpA;
            ((float4*)tp_s)[tid + BLOCKS] = tpB;
        }
        __syncthreads();               // RAW: b-writes -> C-reads

        // ---- c: fused STDP w-update + matvec (bit-exact order: c=0..7, xyzw) ----
        // Do not refactor into FMA (rounding would drift w, can flip spikes).
        const float zi_own = z;        // own neuron's spike (wave-uniform)
        const float tpoi   = tpo_own;  // own neuron's post-trace
        xk = x_s[(k + 1) * ROWS_PER_BLOCK + wv];   // prefetch next input
        float acc = 0.0f;
        const float4* z4s  = (const float4*)z_s;
        const float4* tp4s = (const float4*)tp_s;
        if (zi_own != 0.0f) {
            // own neuron spiked: ORIGINAL expression verbatim (zi_own = 1.0)
            #pragma unroll
            for (int c = 0; c < CHUNKS; ++c) {
                const int slot = c * 32 + perm_base;   // split-slot permutation
                float4 zj = z4s[slot];
                float4 tj = tp4s[slot];
                float nw;
                nw = wreg[c].x + (ETA * (zi_own * tj.x) - ETA * (tpoi * zj.x));
                nw = fminf(fmaxf(nw, 0.0f), 1.0f); wreg[c].x = nw; acc += nw * zj.x;
                nw = wreg[c].y + (ETA * (zi_own * tj.y) - ETA * (tpoi * zj.y));
                nw = fminf(fmaxf(nw, 0.0f), 1.0f); wreg[c].y = nw; acc += nw * zj.y;
                nw = wreg[c].z + (ETA * (zi_own * tj.z) - ETA * (tpoi * zj.z));
                nw = fminf(fmaxf(nw, 0.0f), 1.0f); wreg[c].z = nw; acc += nw * zj.z;
                nw = wreg[c].w + (ETA * (zi_own * tj.w) - ETA * (tpoi * zj.w));
                nw = fminf(fmaxf(nw, 0.0f), 1.0f); wreg[c].w = nw; acc += nw * zj.w;
            }
        } else {
            // zi = 0 fast path, bit-exact (see header proof); tj NOT read.
            const float etp = ETA * tpoi;
            #pragma unroll
            for (int c = 0; c < CHUNKS; ++c) {
                const int slot = c * 32 + perm_base;   // split-slot permutation
                float4 zj = z4s[slot];
                float nw, nwc;
                nwc = fminf(fmaxf(wreg[c].x - etp, 0.0f), 1.0f);
                nw  = (zj.x != 0.0f) ? nwc : wreg[c].x;
                wreg[c].x = nw; acc += nw * zj.x;
                nwc = fminf(fmaxf(wreg[c].y - etp, 0.0f), 1.0f);
                nw  = (zj.y != 0.0f) ? nwc : wreg[c].y;
                wreg[c].y = nw; acc += nw * zj.y;
                nwc = fminf(fmaxf(wreg[c].z - etp, 0.0f), 1.0f);
                nw  = (zj.z != 0.0f) ? nwc : wreg[c].z;
                wreg[c].z = nw; acc += nw * zj.z;
                nwc = fminf(fmaxf(wreg[c].w - etp, 0.0f), 1.0f);
                nw  = (zj.w != 0.0f) ? nwc : wreg[c].w;
                wreg[c].w = nw; acc += nw * zj.w;
            }
        }
        #pragma unroll
        for (int m = 32; m >= 1; m >>= 1) acc += __shfl_xor(acc, m, 64);
        isyn = acc;                    // i_syn for step k+1, in registers

        __syncthreads();               // WAR: C-reads -> next b-writes
    }
}

extern "C" void kernel_launch(void* const* d_in, const int* in_sizes, int n_in,
                              void* d_out, int out_size, void* d_ws, size_t ws_size,
                              hipStream_t stream) {
    const float* x     = (const float*)d_in[0];   // [T,N]
    const float* w_in  = (const float*)d_in[1];   // [N,N]
    const float* tpre  = (const float*)d_in[2];   // [N]
    const float* tpost = (const float*)d_in[3];   // [N]
    float*       out   = (float*)d_out;           // [T,N]

    unsigned long long* zpub = (unsigned long long*)d_ws;

    // Pad each published word to its own line if the workspace allows:
    // 128B stride (TCC line) needs 64KB, 64B needs 32KB, else packed (4KB).
    int stride;
    if      (ws_size >= (size_t)2 * BLOCKS * 16 * sizeof(unsigned long long)) stride = 16;
    else if (ws_size >= (size_t)2 * BLOCKS *  8 * sizeof(unsigned long long)) stride = 8;
    else                                                                      stride = 1;

    void* args[] = {(void*)&x, (void*)&w_in, (void*)&tpre, (void*)&tpost,
                    (void*)&zpub, (void*)&stride, (void*)&out};
    hipLaunchCooperativeKernel((void*)snn_msg_kernel,
                               dim3(BLOCKS), dim3(THREADS),
                               args, 0, stream);
}

// Round 12
// 262.338 us; speedup vs baseline: 1.8240x; 1.1958x over previous
//
#include <hip/hip_runtime.h>

// Problem constants (match reference)
constexpr int   T_STEPS = 64;
constexpr int   NN      = 2048;
constexpr float DT_TAU  = 0.1f;    // DT * TAU_MEM_INV
constexpr float V_TH_C  = 1.0f;
constexpr float TRC     = 0.05f;   // DT * TAU_PRE_INV == DT * TAU_POST_INV
constexpr float ETA     = 1e-3f;   // ETA_PLUS == ETA_MINUS

// 256 blocks x 512 threads (cooperative, 1 block/CU). Block b owns neurons
// [8b, 8b+8); wave w owns neuron 8b+w (w-row in 32 VGPR/lane; v/tpo/isyn
// replicated across its 64 lanes). z/tp replicated per block in LDS (split-
// slot layout), rebuilt each step from the published spike words.
//
// THIS IS THE ROUND-6 KERNEL, RESTORED VERBATIM — the empirical optimum
// (180.3 us dispatch) across 11 structural variants.
//
// HARD-WON EXCHANGE RULES (r1/r2/r4/r5/r8/r9/r10/r11):
//  1. Private 128B line per published word (r2: 244->203).
//  2. EXACTLY 256 pollers/block, one word each (r5: 512/line -> +36us;
//     agent-scope atomic loads issue per-lane, no same-address merge).
//  3. Publish by the 8th arriver via LDS RMW (r4: 203->181).
//  4. NO scattered fan-out stores (r9 push-mailboxes: 129MB HBM writeback,
//     +51us). Fan-in polling is cheaper than fan-out storing.
//  5. LDS bank conflicts of 2-8M are hidden under the exchange wait
//     (r4 2.58M == r6 8.26M == ~181us).
//  6. NO extra machinery in the exchange: poll-prefetch/one-barrier (r8,
//     +51us) and arrival-ordered consumption (r10, +221us) lost to their
//     own overhead.
//  7. NO data-dependent branches in phase C (r11 zi=0 fast path: +54us of
//     lgkmcnt stall — the branch defeats the compiler's LDS-load
//     pipelining; uniform branch-free code beats fewer ops here).
//
// Step k:
//  a. LIF from register isyn -> z; v,tpo in regs; lane0: raster store +
//     ds-atomic arrive on word_s[par] (add (1<<24)|(z<<wv)); 8th arriver
//     publishes ONE tagged u64 ((k+1)<<32|bits) to this block's line.
//  b. pollers tid<256 spin on word tid (tag k+1), unpack 8 neurons into
//     z_s split-slots (slot tid = neurons [8tid,8tid+4), slot tid+256 =
//     [8tid+4,8tid+8): both stores stride-1); tp persistent in poller regs.
//     __syncthreads  (RAW: b-writes visible before C-reads)
//  c. fused STDP w-update + matvec, split-slot permuted reads
//     (slot = c*32 + (lane>>1) + 256*(lane&1)), bit-exact c=0..7/xyzw order,
//     single uniform path. Butterfly -> isyn in regs; prefetch next x.
//     __syncthreads  (WAR: C-reads done before next b-writes; also orders
//                     word_s reset (a) before k+2 arrivals on that parity)
//
// Cross-block safety: message==data (bits ride in the tagged word, single 8B
// atomic); tags 1..64 never match 0x00/0xAA poison; parity double-buffer +
// publish gating chain (publish(k+2) transitively requires every block's
// pollers consumed tag k+1) -> '!=' spin never misses; no ws init needed.
constexpr int BLOCKS  = 256;
constexpr int THREADS = 512;
constexpr int ROWS_PER_BLOCK = NN / BLOCKS;   // 8 == waves per block
constexpr int CHUNKS = NN / 256;              // 8 float4 chunks per lane

__global__ __launch_bounds__(THREADS)
void snn_msg_kernel(const float* __restrict__ x,       // [T, N]
                    const float* __restrict__ w_in,    // [N, N] pristine (never written)
                    const float* __restrict__ tpre0,   // [N]
                    const float* __restrict__ tpost0,  // [N]
                    unsigned long long* __restrict__ zpub, // [2][BLOCKS*stride]
                    int stride,                        // u64 units between words
                    float*       __restrict__ out)     // [T, N] spikes
{
    const int bid  = blockIdx.x;
    const int tid  = threadIdx.x;
    const int wv   = tid >> 6;
    const int lane = tid & 63;
    const int row  = bid * ROWS_PER_BLOCK + wv;   // this wave's neuron / w row

    __shared__ __align__(16) float z_s[NN];       // spike vector (split-slot layout)
    __shared__ __align__(16) float tp_s[NN];      // pre-trace mirror (split-slot)
    __shared__ __align__(16) float x_s[T_STEPS * ROWS_PER_BLOCK]; // owned inputs
    __shared__ unsigned word_s[2];                // [parity] count<<24 | bits

    // Poller tid (<256) owns neurons [8tid, 8tid+8): tp persistent in regs.
    float4 tpA = make_float4(0.f, 0.f, 0.f, 0.f);
    float4 tpB = tpA;
    if (tid < BLOCKS) {
        tpA = ((const float4*)tpre0)[2 * tid];
        tpB = ((const float4*)tpre0)[2 * tid + 1];
    }

    // Stage ALL owned inputs x[t][8b..8b+8) into LDS once.
    x_s[tid] = x[(size_t)(tid >> 3) * NN + bid * ROWS_PER_BLOCK + (tid & 7)];

    if (tid < 2) word_s[tid] = 0u;

    // Own-neuron state, replicated across all 64 lanes.
    float v_own   = 0.0f;
    float tpo_own = tpost0[row];          // broadcast load

    // This wave's w row: chunk c holds w[row][(c*64+lane)*4 ..+3].
    const float4* wrow4 = (const float4*)(w_in + (size_t)row * NN);
    float4 wreg[CHUNKS];
    #pragma unroll
    for (int c = 0; c < CHUNKS; ++c) wreg[c] = wrow4[c * 64 + lane];

    // Per-lane constant base for the split-slot permutation (phase C reads).
    const int perm_base = (lane >> 1) + 256 * (lane & 1);

    float isyn = 0.0f;                    // w @ z carry, lives in registers
    float xk   = 0.0f;                    // prefetched input current
    __syncthreads();
    xk = x_s[wv];                         // x[0][row] (post-barrier: x_s ready)

    for (int k = 0; k < T_STEPS; ++k) {
        const int par = k & 1;

        // ---- a: LIF (all lanes redundantly); lane0 raster + arrive/publish ----
        float v = v_own + DT_TAU * ((0.0f - v_own) + isyn + xk);
        float z = (v - V_TH_C > 0.0f) ? 1.0f : 0.0f;
        v_own   = v * (1.0f - z);
        tpo_own = tpo_own + TRC * (-tpo_own + z);   // post-trace (post-update
                                                    // value feeds C, as in ref)
        if (lane == 0) {
            out[(size_t)k * NN + row] = z;          // fire-and-forget raster
            if (k + 1 < T_STEPS) {
                unsigned add = 0x01000000u | (z > 0.0f ? (1u << wv) : 0u);
                unsigned old = __hip_atomic_fetch_add(&word_s[par], add,
                                   __ATOMIC_RELAXED, __HIP_MEMORY_SCOPE_WORKGROUP);
                if ((old >> 24) == 7u) {            // 8th arriver publishes
                    unsigned bits = (old + add) & 0xFFu;
                    // reset for reuse at k+2; ordered before k+2 arrivals by
                    // the post-b and post-C barriers of iterations k and k+1.
                    __hip_atomic_store(&word_s[par], 0u,
                                       __ATOMIC_RELAXED, __HIP_MEMORY_SCOPE_WORKGROUP);
                    unsigned long long wrd =
                        ((unsigned long long)(unsigned)(k + 1) << 32) | bits;
                    __hip_atomic_store(&zpub[(size_t)(par * BLOCKS + bid) * stride],
                                       wrd, __ATOMIC_RELAXED,
                                       __HIP_MEMORY_SCOPE_AGENT);
                }
            }
        }
        if (k == T_STEPS - 1) break;   // raster[63] written; no exchange needed

        // ---- b: 256 pollers, one word each; in-place unpack to split slots ----
        if (tid < BLOCKS) {
            const unsigned long long* p =
                &zpub[(size_t)(par * BLOCKS + tid) * stride];
            unsigned long long pv = __hip_atomic_load(p, __ATOMIC_RELAXED,
                                        __HIP_MEMORY_SCOPE_AGENT);
            while ((unsigned)(pv >> 32) != (unsigned)(k + 1)) {
                __builtin_amdgcn_s_sleep(1);   // ~64cy backoff
                pv = __hip_atomic_load(p, __ATOMIC_RELAXED,
                                       __HIP_MEMORY_SCOPE_AGENT);
            }
            const unsigned bits = (unsigned)pv;   // z of neurons 8*tid..8*tid+7
            float4 zA, zB;
            zA.x = (bits & 0x01u) ? 1.0f : 0.0f;
            zA.y = (bits & 0x02u) ? 1.0f : 0.0f;
            zA.z = (bits & 0x04u) ? 1.0f : 0.0f;
            zA.w = (bits & 0x08u) ? 1.0f : 0.0f;
            zB.x = (bits & 0x10u) ? 1.0f : 0.0f;
            zB.y = (bits & 0x20u) ? 1.0f : 0.0f;
            zB.z = (bits & 0x40u) ? 1.0f : 0.0f;
            zB.w = (bits & 0x80u) ? 1.0f : 0.0f;
            // identical per-element expression as always -> bit-exact
            tpA.x = tpA.x + TRC * (-tpA.x + zA.x);
            tpA.y = tpA.y + TRC * (-tpA.y + zA.y);
            tpA.z = tpA.z + TRC * (-tpA.z + zA.z);
            tpA.w = tpA.w + TRC * (-tpA.w + zA.w);
            tpB.x = tpB.x + TRC * (-tpB.x + zB.x);
            tpB.y = tpB.y + TRC * (-tpB.y + zB.y);
            tpB.z = tpB.z + TRC * (-tpB.z + zB.z);
            tpB.w = tpB.w + TRC * (-tpB.w + zB.w);
            // split-slot stores: both instructions stride-1 across the wave
            ((float4*)z_s)[tid]          = zA;
            ((float4*)z_s)[tid + BLOCKS] = zB;
            ((float4*)tp_s)[tid]          = tpA;
            ((float4*)tp_s)[tid + BLOCKS] = tpB;
        }
        __syncthreads();               // RAW: b-writes -> C-reads

        // ---- c: fused STDP w-update + matvec (bit-exact order: c=0..7, xyzw) ----
        // Do not refactor into FMA (rounding would drift w, can flip spikes).
        // Single uniform path — no data-dependent branch (rule 7).
        const float zi_own = z;        // own neuron's spike
        const float tpoi   = tpo_own;  // own neuron's post-trace
        xk = x_s[(k + 1) * ROWS_PER_BLOCK + wv];   // prefetch next input
        float acc = 0.0f;
        const float4* z4s  = (const float4*)z_s;
        const float4* tp4s = (const float4*)tp_s;
        #pragma unroll
        for (int c = 0; c < CHUNKS; ++c) {
            const int slot = c * 32 + perm_base;   // split-slot permutation
            float4 zj = z4s[slot];
            float4 tj = tp4s[slot];
            float nw;
            nw = wreg[c].x + (ETA * (zi_own * tj.x) - ETA * (tpoi * zj.x));
            nw = fminf(fmaxf(nw, 0.0f), 1.0f); wreg[c].x = nw; acc += nw * zj.x;
            nw = wreg[c].y + (ETA * (zi_own * tj.y) - ETA * (tpoi * zj.y));
            nw = fminf(fmaxf(nw, 0.0f), 1.0f); wreg[c].y = nw; acc += nw * zj.y;
            nw = wreg[c].z + (ETA * (zi_own * tj.z) - ETA * (tpoi * zj.z));
            nw = fminf(fmaxf(nw, 0.0f), 1.0f); wreg[c].z = nw; acc += nw * zj.z;
            nw = wreg[c].w + (ETA * (zi_own * tj.w) - ETA * (tpoi * zj.w));
            nw = fminf(fmaxf(nw, 0.0f), 1.0f); wreg[c].w = nw; acc += nw * zj.w;
        }
        #pragma unroll
        for (int m = 32; m >= 1; m >>= 1) acc += __shfl_xor(acc, m, 64);
        isyn = acc;                    // i_syn for step k+1, in registers

        __syncthreads();               // WAR: C-reads -> next b-writes
    }
}

extern "C" void kernel_launch(void* const* d_in, const int* in_sizes, int n_in,
                              void* d_out, int out_size, void* d_ws, size_t ws_size,
                              hipStream_t stream) {
    const float* x     = (const float*)d_in[0];   // [T,N]
    const float* w_in  = (const float*)d_in[1];   // [N,N]
    const float* tpre  = (const float*)d_in[2];   // [N]
    const float* tpost = (const float*)d_in[3];   // [N]
    float*       out   = (float*)d_out;           // [T,N]

    unsigned long long* zpub = (unsigned long long*)d_ws;

    // Pad each published word to its own line if the workspace allows:
    // 128B stride (TCC line) needs 64KB, 64B needs 32KB, else packed (4KB).
    int stride;
    if      (ws_size >= (size_t)2 * BLOCKS * 16 * sizeof(unsigned long long)) stride = 16;
    else if (ws_size >= (size_t)2 * BLOCKS *  8 * sizeof(unsigned long long)) stride = 8;
    else                                                                      stride = 1;

    void* args[] = {(void*)&x, (void*)&w_in, (void*)&tpre, (void*)&tpost,
                    (void*)&zpub, (void*)&stride, (void*)&out};
    hipLaunchCooperativeKernel((void*)snn_msg_kernel,
                               dim3(BLOCKS), dim3(THREADS),
                               args, 0, stream);
}